// Round 7
// baseline (217.366 us; speedup 1.0000x reference)
//
#include <hip/hip_runtime.h>
#include <math.h>

typedef _Float16 f16;
typedef _Float16 half8 __attribute__((ext_vector_type(8)));
typedef float f32x16 __attribute__((ext_vector_type(16)));
typedef float f32x2  __attribute__((ext_vector_type(2)));

#define DEV __device__ __forceinline__

// ---------------- workspace layout (bytes) ----------------
#define W1F_OFF 0        // [L][nt2]      : 16 frags  = 16 KB   (x 2*log2e)
#define W2F_OFF 16384    // [L][kt4][nt2] : 64 frags  = 64 KB   (unscaled)
#define WOF_OFF 81920    // [L][u8][kt4]  : 256 frags = 256 KB  (x log2e)
#define BOF_OFF 344064   // [L][u8][32] fp32 bias (x log2e, +offset folded) = 8 KB
#define SUMLOG_OFF 352256 // 1 fp32: sum over all layers/features of log|scale|
#define W0S_OFF 352320   // [L][16][16] f32 W0 x 2*log2e = 8 KB
#define B0S_OFF 360512   // [L][16]     f32 b0 x 2*log2e = 512 B
#define B1S_OFF 361088   // [L][64]     f32 b1 x 2*log2e = 2 KB (end 363136)

// ---------------- LDS: PER-WAVE ARENA (19712 B), 4 waves/block -------------
// Every region of a wave's arena lies in [wv*ARENA, (wv+1)*ARENA) — ALL
// traffic is genuinely wave-private (round-6 bug: block-global region bases
// with different strides made P1 of wave w overlap H0/H of wave w+1 -> race).
// Within one wave, DS ops execute in program order, so P1 may alias H0+H:
// the a2 register reads (last H use) precede all P1 stores; the next layer's
// H0 writes follow this layer's last P1 read.
//   H0 : [64][48]  f16 h0 staging      @ arena+0      (3072)
//   H  : [64][144] f16 h1/h2 staging   @ arena+3072   (9216, ends 12288)
//   P0 : [64][116] f32 params even u   @ arena+12288  (7424, ends 19712)
//   P1 : [64][116] f32 params odd  u   @ arena+0      (aliases H0+H, 7424<=12288)
#define H0_OFF    0
#define H0_STRIDE 48
#define H_OFF     3072
#define H_STRIDE  144
#define P0_OFF    12288
#define P1_OFF    0
#define P_STRIDE  116
#define ARENA     19712
#define LDS_BYTES (4 * ARENA)   // 78848, same as round 5 -> 2 blocks/CU

DEV float frcp(float x){ return __builtin_amdgcn_rcpf(x); }

#if __has_builtin(__builtin_amdgcn_exp2f)
DEV float fexp2(float x){ return __builtin_amdgcn_exp2f(x); }
#else
DEV float fexp2(float x){ return exp2f(x); }
#endif
#if __has_builtin(__builtin_amdgcn_logf)
DEV float flog2(float x){ return __builtin_amdgcn_logf(x); }
#else
DEV float flog2(float x){ return log2f(x); }
#endif

#define LN2F    0.69314718056f
#define LOG2EF  1.4426950409f
#define TWOLOG2EF 2.8853900818f

// tanh with PRE-SCALED input: x' = 2*log2e * x_linear.
// tanh = 1 - 2/(2^{x'}+1). Robust without clamp. 4 instructions.
DEV float ftanh2(float x){
  float e = fexp2(x);
  float r = frcp(e + 1.f);
  return fmaf(-2.f, r, 1.f);
}

// Rational-quadratic spline forward + log-det (fp32, per-thread).
// p in LOG2 DOMAIN (params x log2e, softplus offset pre-folded at prep).
// ld_out returned in log2 units. Softmax denominators tree-reduced.
DEV void rq_spline(const float p[25], float xv, float &y_out, float &ld_out)
{
  float ew[8];
#pragma unroll
  for (int k = 0; k < 8; ++k) ew[k] = fexp2(p[k]);
  float sw = ((ew[0]+ew[1])+(ew[2]+ew[3])) + ((ew[4]+ew[5])+(ew[6]+ew[7]));
  float rw = frcp(sw) * 19.9992f;           // (RMAX-RMIN) - K*MIN_BIN

  float xpos[9];
  xpos[0] = -10.f;
#pragma unroll
  for (int k = 0; k < 8; ++k) xpos[k + 1] = xpos[k] + fmaf(ew[k], rw, 1e-4f);

  bool b[8];
  int idx = 0;
#pragma unroll
  for (int j = 1; j < 8; ++j){ b[j] = (xv >= xpos[j]); idx += b[j] ? 1 : 0; }

  float xk = xpos[0], ewk = ew[0];
#pragma unroll
  for (int j = 1; j < 8; ++j){
    xk  = b[j] ? xpos[j] : xk;
    ewk = b[j] ? ew[j]   : ewk;
  }
  float bw = fmaf(ewk, rw, 1e-4f);

  float eh[8];
#pragma unroll
  for (int k = 0; k < 8; ++k) eh[k] = fexp2(p[8 + k]);
  float shs = ((eh[0]+eh[1])+(eh[2]+eh[3])) + ((eh[4]+eh[5])+(eh[6]+eh[7]));
  float rh = frcp(shs) * 19.9992f;

  float S = 0.f, ehk = eh[0];
#pragma unroll
  for (int k = 1; k < 8; ++k){
    S   += b[k] ? eh[k - 1] : 0.f;
    ehk  = b[k] ? eh[k]     : ehk;
  }
  float yk = fmaf(S, rh, fmaf((float)idx, 1e-4f, -10.f));
  float bh = fmaf(ehk, rh, 1e-4f);

  float vA = p[16], vB = p[17];
#pragma unroll
  for (int j = 1; j < 8; ++j){
    vA = b[j] ? p[16 + j] : vA;
    vB = b[j] ? p[17 + j] : vB;
  }
  // softplus in log2 domain: ln(1+e^u) = ln2*(max(v,0)+log2(1+2^{-|v|}))
  float tA = fmaxf(vA, 0.f) + flog2(1.f + fexp2(-fabsf(vA)));
  float dk  = fmaf(LN2F, tA, 1e-4f);
  float tB = fmaxf(vB, 0.f) + flog2(1.f + fexp2(-fabsf(vB)));
  float dk1 = fmaf(LN2F, tB, 1e-4f);

  float rbw = frcp(bw);
  float s   = bh * rbw;
  float zf  = fminf(fmaxf((xv - xk) * rbw, 0.f), 1.f);
  float z1  = 1.f - zf;
  float zz  = zf * zf, z01 = zf * z1;
  float den = s + (dk1 + dk - 2.f * s) * z01;
  float rden = frcp(den);
  float yv  = yk + bh * (s * zz + dk * z01) * rden;
  float num = dk1 * zz + 2.f * s * z01 + dk * z1 * z1;
  float ldv2 = flog2(s * s * num * rden * rden);   // log2-domain

  bool outside = (xv <= -10.f) || (xv >= 10.f);
  y_out  = outside ? xv : yv;
  ld_out = outside ? 0.f : ldv2;
}

// ---------------- prep kernel: pack fp16 B-fragments into ws ----------------
// Scaling folded in: W1/b1/W0/b0 x 2*log2e (tanh exp2 path), Wout/bout
// x log2e (+ softplus offset into bout cols 16..24). W2/b2 UNscaled.
extern "C" __global__ void __launch_bounds__(256)
prep_kernel(const float* __restrict__ W0, const float* __restrict__ b0,
            const float* __restrict__ W1, const float* __restrict__ b1,
            const float* __restrict__ W2,
            const float* __restrict__ Wo, const float* __restrict__ bout,
            const float* __restrict__ scale, char* __restrict__ ws)
{
  int tid = blockIdx.x * 256 + threadIdx.x;
  if (tid < 1024){                       // W1 frags: [L][nt2]  (x 2*log2e)
    int fi = tid >> 6, lane = tid & 63;
    int l = fi >> 1, nt = fi & 1;
    int n = nt * 32 + (lane & 31), khi = lane >> 5;
    half8 h;
#pragma unroll
    for (int j = 0; j < 8; ++j){ int k = khi * 8 + j; h[j] = (f16)(W1[l * 1024 + k * 64 + n] * TWOLOG2EF); }
    *(half8*)(ws + W1F_OFF + fi * 1024 + lane * 16) = h;
  } else if (tid < 5120){                // W2 frags: [L][kt4][nt2] (unscaled)
    int idx = tid - 1024;
    int fi = idx >> 6, lane = idx & 63;
    int l = fi >> 3, kt = (fi >> 1) & 3, nt = fi & 1;
    int n = nt * 32 + (lane & 31), khi = lane >> 5;
    half8 h;
#pragma unroll
    for (int j = 0; j < 8; ++j){ int k = kt * 16 + khi * 8 + j; h[j] = (f16)W2[l * 4096 + k * 64 + n]; }
    *(half8*)(ws + W2F_OFF + fi * 1024 + lane * 16) = h;
  } else if (tid < 21504){               // Wout used-col frags: [L][u8][kt4] (x log2e)
    int idx = tid - 5120;
    int fi = idx >> 6, lane = idx & 63;
    int l = fi >> 5, u = (fi >> 2) & 7, kt = fi & 3;
    int f = (l & 1) + 2 * u;
    int c = lane & 31, khi = lane >> 5;
    half8 h;
#pragma unroll
    for (int j = 0; j < 8; ++j){
      int k = kt * 16 + khi * 8 + j;
      float v = (c < 25) ? Wo[l * 25600 + k * 400 + f * 25 + c] * LOG2EF : 0.f;
      h[j] = (f16)v;
    }
    *(half8*)(ws + WOF_OFF + fi * 1024 + lane * 16) = h;
  } else if (tid < 23552){               // bout used cols: [L][u8][32] fp32
    int idx = tid - 21504;
    int l = idx >> 8, u = (idx >> 5) & 7, c = idx & 31;
    int f = (l & 1) + 2 * u;
    float v = 0.f;
    if (c < 25){
      v = bout[l * 400 + f * 25 + c];
      if (c >= 16) v += 0.54116666f;     // softplus offset folded
      v *= LOG2EF;
    }
    ((float*)(ws + BOF_OFF))[idx] = v;
  } else if (tid == 23552){              // sum of log|scale| over all layers
    float acc = 0.f;
    for (int i = 0; i < 128; ++i) acc += logf(fabsf(scale[i]));
    *(float*)(ws + SUMLOG_OFF) = acc;
  } else if (tid < 25601){               // W0 scaled copy: 2048 floats
    int idx = tid - 23553;
    ((float*)(ws + W0S_OFF))[idx] = W0[idx] * TWOLOG2EF;
  } else if (tid < 25729){               // b0 scaled copy: 128 floats
    int idx = tid - 25601;
    ((float*)(ws + B0S_OFF))[idx] = b0[idx] * TWOLOG2EF;
  } else if (tid < 26241){               // b1 scaled copy: 512 floats
    int idx = tid - 25729;
    ((float*)(ws + B1S_OFF))[idx] = b1[idx] * TWOLOG2EF;
  }
}

// ---- Wout feature MFMA + guarded P-store (one feature -> one P slot) ----
// ldsw = this wave's arena base; rows are wave-local (0..63).
DEV void wout_feature(const half8 (&a2)[2][4], const half8 (&bfn)[4], float biasn,
                      char* ldsw, int poff, int ln31, int rowbase)
{
  f32x16 dp[2];
#pragma unroll
  for (int mt = 0; mt < 2; ++mt)
#pragma unroll
    for (int i = 0; i < 16; ++i) dp[mt][i] = biasn;
#pragma unroll
  for (int kt = 0; kt < 4; ++kt)
#pragma unroll
    for (int mt = 0; mt < 2; ++mt)
      dp[mt] = __builtin_amdgcn_mfma_f32_32x32x16_f16(a2[mt][kt], bfn[kt], dp[mt], 0, 0, 0);
  if (ln31 < 25){
#pragma unroll
    for (int mt = 0; mt < 2; ++mt)
#pragma unroll
      for (int i = 0; i < 16; ++i){
        int row = (i & 3) + 8 * (i >> 2) + rowbase;
        int s = mt * 32 + row;
        *(float*)(ldsw + poff + s * P_STRIDE + ln31 * 4) = dp[mt][i];
      }
  }
}

// ---------------- one coupling layer (arena = wave-private LDS) ------------
// 64 samples/wave, 1 lane/sample (proven). Feature phase: PAIRWISE software
// pipeline over two P slots — features u (even->P0) and u+1 (odd->P1) read
// back-to-back, next pair's MFMA+stores issued, then TWO independent splines
// interleave their trans/VALU chains. All z/p indices compile-time.
template<int PAR>
DEV void layer_mfma(int l,
                    const float* __restrict__ b2v,
                    const float* __restrict__ scv, const float* __restrict__ shv,
                    const char* __restrict__ ws, char* ldsw,
                    float (&z)[16], float &logdet,
                    int lane, int ln31, int khi)
{
  const float* w0  = (const float*)(ws + W0S_OFF) + l * 256;   // x 2*log2e
  const float* bb0 = (const float*)(ws + B0S_OFF) + l * 16;    // x 2*log2e
  const int rowbase = khi * 4;     // C/D layout: row = (i&3)+8*(i>>2)+4*(lane>>5)

  // ---- hoisted weight-fragment loads (latency hidden behind h0 VALU) ----
  const half8* W1F = (const half8*)(ws + W1F_OFF);
  const half8* W2F = (const half8*)(ws + W2F_OFF);
  half8 w1f[2];
#pragma unroll
  for (int nt = 0; nt < 2; ++nt) w1f[nt] = W1F[(l * 2 + nt) * 64 + lane];
  half8 w2f[8];
#pragma unroll
  for (int kt = 0; kt < 4; ++kt)
#pragma unroll
    for (int nt = 0; nt < 2; ++nt)
      w2f[kt * 2 + nt] = W2F[((l * 4 + kt) * 2 + nt) * 64 + lane];
  float bias1[2], bias2[2];
#pragma unroll
  for (int nt = 0; nt < 2; ++nt){
    bias1[nt] = ((const float*)(ws + B1S_OFF))[l * 64 + nt * 32 + ln31]; // x 2*log2e
    bias2[nt] = b2v[l * 64 + nt * 32 + ln31];                            // unscaled
  }

  // ---- h0 = tanh(mz @ W0 + b0), per-thread VALU (f32x2 -> v_pk_fma_f32) --
  f32x2 h0p[8];
  const f32x2* bb0v = (const f32x2*)bb0;
#pragma unroll
  for (int j = 0; j < 8; ++j) h0p[j] = bb0v[j];
#pragma unroll
  for (int u = 0; u < 8; ++u){
    const int f = (1 - PAR) + 2 * u;
    const float v = z[f];
    f32x2 vv; vv[0] = v; vv[1] = v;
    const f32x2* w0v = (const f32x2*)(w0 + f * 16);
#pragma unroll
    for (int j = 0; j < 8; ++j) h0p[j] = vv * w0v[j] + h0p[j];
  }
  {
    half8 lo, hi;
#pragma unroll
    for (int j = 0; j < 4; ++j){
      lo[2*j]   = (f16)ftanh2(h0p[j][0]);
      lo[2*j+1] = (f16)ftanh2(h0p[j][1]);
      hi[2*j]   = (f16)ftanh2(h0p[4+j][0]);
      hi[2*j+1] = (f16)ftanh2(h0p[4+j][1]);
    }
    *(half8*)(ldsw + H0_OFF + lane * H0_STRIDE)      = lo;
    *(half8*)(ldsw + H0_OFF + lane * H0_STRIDE + 16) = hi;
  }

  // ---- W1: h1 = tanh(h0 @ W1 + b1) via MFMA (bias folded into acc init) ----
  half8 a0[2];
#pragma unroll
  for (int mt = 0; mt < 2; ++mt){
    int s = mt * 32 + ln31;
    a0[mt] = *(const half8*)(ldsw + H0_OFF + s * H0_STRIDE + khi * 16);
  }
  f32x16 d1[2][2];
#pragma unroll
  for (int mt = 0; mt < 2; ++mt)
#pragma unroll
    for (int nt = 0; nt < 2; ++nt)
#pragma unroll
      for (int i = 0; i < 16; ++i) d1[mt][nt][i] = bias1[nt];
#pragma unroll
  for (int nt = 0; nt < 2; ++nt)
#pragma unroll
    for (int mt = 0; mt < 2; ++mt)
      d1[mt][nt] = __builtin_amdgcn_mfma_f32_32x32x16_f16(a0[mt], w1f[nt], d1[mt][nt], 0, 0, 0);
#pragma unroll
  for (int mt = 0; mt < 2; ++mt)
#pragma unroll
    for (int nt = 0; nt < 2; ++nt)
#pragma unroll
      for (int i = 0; i < 16; ++i){
        int row = (i & 3) + 8 * (i >> 2) + rowbase;
        int s = mt * 32 + row;
        float v = ftanh2(d1[mt][nt][i]);
        *(f16*)(ldsw + H_OFF + s * H_STRIDE + (nt * 32 + ln31) * 2) = (f16)v;
      }

  // ---- W2: h2 = h1 @ W2 + b2 via MFMA (bias folded) ----
  half8 a1[2][4];
#pragma unroll
  for (int mt = 0; mt < 2; ++mt){
    int s = mt * 32 + ln31;
#pragma unroll
    for (int kt = 0; kt < 4; ++kt)
      a1[mt][kt] = *(const half8*)(ldsw + H_OFF + s * H_STRIDE + kt * 32 + khi * 16);
  }
  f32x16 d2[2][2];
#pragma unroll
  for (int mt = 0; mt < 2; ++mt)
#pragma unroll
    for (int nt = 0; nt < 2; ++nt)
#pragma unroll
      for (int i = 0; i < 16; ++i) d2[mt][nt][i] = bias2[nt];
#pragma unroll
  for (int kt = 0; kt < 4; ++kt)
#pragma unroll
    for (int nt = 0; nt < 2; ++nt)
#pragma unroll
      for (int mt = 0; mt < 2; ++mt)
        d2[mt][nt] = __builtin_amdgcn_mfma_f32_32x32x16_f16(a1[mt][kt], w2f[kt * 2 + nt], d2[mt][nt], 0, 0, 0);

  // ---- prefetch features u=0,1 Wout frags (hidden behind W2 epilogue) ----
  const half8* WOF = (const half8*)(ws + WOF_OFF);
  const float* BOF = (const float*)(ws + BOF_OFF);
  half8 bfnA[4], bfnB[4]; float biasnA, biasnB;
#pragma unroll
  for (int kt = 0; kt < 4; ++kt){
    bfnA[kt] = WOF[((l * 8 + 0) * 4 + kt) * 64 + lane];
    bfnB[kt] = WOF[((l * 8 + 1) * 4 + kt) * 64 + lane];
  }
  biasnA = BOF[(l * 8 + 0) * 32 + ln31];
  biasnB = BOF[(l * 8 + 1) * 32 + ln31];

#pragma unroll
  for (int mt = 0; mt < 2; ++mt)
#pragma unroll
    for (int nt = 0; nt < 2; ++nt)
#pragma unroll
      for (int i = 0; i < 16; ++i){
        int row = (i & 3) + 8 * (i >> 2) + rowbase;
        int s = mt * 32 + row;
        float v = d2[mt][nt][i];
        *(f16*)(ldsw + H_OFF + s * H_STRIDE + (nt * 32 + ln31) * 2) = (f16)v;
      }

  // ---- h2 A-fragments (reused across all 8 features). After these reads
  //      the H0/H regions of THIS wave's arena are dead -> P1 may alias. ----
  half8 a2[2][4];
#pragma unroll
  for (int mt = 0; mt < 2; ++mt){
    int s = mt * 32 + ln31;
#pragma unroll
    for (int kt = 0; kt < 4; ++kt)
      a2[mt][kt] = *(const half8*)(ldsw + H_OFF + s * H_STRIDE + kt * 32 + khi * 16);
  }

  // ---- pairwise feature pipeline over two P slots ----
  // pre-loop: p(0)->P0, p(1)->P1; prefetch Wout for u=2,3
  wout_feature(a2, bfnA, biasnA, ldsw, P0_OFF, ln31, rowbase);
  wout_feature(a2, bfnB, biasnB, ldsw, P1_OFF, ln31, rowbase);
#pragma unroll
  for (int kt = 0; kt < 4; ++kt){
    bfnA[kt] = WOF[((l * 8 + 2) * 4 + kt) * 64 + lane];
    bfnB[kt] = WOF[((l * 8 + 3) * 4 + kt) * 64 + lane];
  }
  biasnA = BOF[(l * 8 + 2) * 32 + ln31];
  biasnB = BOF[(l * 8 + 3) * 32 + ln31];

#pragma unroll
  for (int vp = 0; vp < 4; ++vp){
    // read both features' params back-to-back (slots already valid)
    float pa[25], pb[25];
#pragma unroll
    for (int j = 0; j < 25; ++j)
      pa[j] = *(const float*)(ldsw + P0_OFF + lane * P_STRIDE + j * 4);
#pragma unroll
    for (int j = 0; j < 25; ++j)
      pb[j] = *(const float*)(ldsw + P1_OFF + lane * P_STRIDE + j * 4);

    // issue next pair's MFMAs + stores (reads above precede in program order)
    if (vp < 3){
      wout_feature(a2, bfnA, biasnA, ldsw, P0_OFF, ln31, rowbase);
      wout_feature(a2, bfnB, biasnB, ldsw, P1_OFF, ln31, rowbase);
      if (vp < 2){
#pragma unroll
        for (int kt = 0; kt < 4; ++kt){
          bfnA[kt] = WOF[((l * 8 + 2 * vp + 4) * 4 + kt) * 64 + lane];
          bfnB[kt] = WOF[((l * 8 + 2 * vp + 5) * 4 + kt) * 64 + lane];
        }
        biasnA = BOF[(l * 8 + 2 * vp + 4) * 32 + ln31];
        biasnB = BOF[(l * 8 + 2 * vp + 5) * 32 + ln31];
      }
    }

    // two independent splines — scheduler interleaves their chains
    const int fa = PAR + 4 * vp;       // feature of u=2vp   (compile-time)
    const int fb = fa + 2;             // feature of u=2vp+1 (compile-time)
    float ya, lda, yb, ldb;
    rq_spline(pa, z[fa], ya, lda);
    rq_spline(pb, z[fb], yb, ldb);
    z[fa] = ya;
    z[fb] = yb;
    logdet += lda + ldb;
  }

  // ---- affine (log|scale| sum precomputed in prep) ----
  const float* scp = scv + l * 16;
  const float* shp = shv + l * 16;
#pragma unroll
  for (int j = 0; j < 16; ++j)
    z[j] = fmaf(z[j], scp[j], shp[j]);
}

extern "C" __global__ void __launch_bounds__(256, 2)
flow_kernel(const float* __restrict__ x,
            const float* __restrict__ b2v,
            const float* __restrict__ scv, const float* __restrict__ shv,
            const char* __restrict__ ws, float* __restrict__ out, int B)
{
  extern __shared__ char lds[];
  const int t    = threadIdx.x;
  const int lane = t & 63;
  const int wv   = t >> 6;
  const int ln31 = lane & 31;
  const int khi  = lane >> 5;
  char* ldsw = lds + wv * ARENA;          // wave-private arena
  const int g    = blockIdx.x * 256 + t;

  float z[16];
  const float4* xv = reinterpret_cast<const float4*>(x + (size_t)g * 16);
  float4 a0 = xv[0], a1 = xv[1], a2 = xv[2], a3 = xv[3];
  z[0]=a0.x; z[1]=a0.y; z[2]=a0.z; z[3]=a0.w;
  z[4]=a1.x; z[5]=a1.y; z[6]=a1.z; z[7]=a1.w;
  z[8]=a2.x; z[9]=a2.y; z[10]=a2.z; z[11]=a2.w;
  z[12]=a3.x; z[13]=a3.y; z[14]=a3.z; z[15]=a3.w;

  float logdet = 0.f;                 // in log2 units
  for (int l = 7; l >= 0; --l){
    if (l & 1) layer_mfma<1>(l, b2v, scv, shv, ws, ldsw, z, logdet, lane, ln31, khi);
    else       layer_mfma<0>(l, b2v, scv, shv, ws, ldsw, z, logdet, lane, ln31, khi);
  }

  float sumlog = *(const float*)(ws + SUMLOG_OFF);
  float ss = 0.f;
#pragma unroll
  for (int j = 0; j < 16; ++j) ss = fmaf(z[j], z[j], ss);
  out[g] = fmaf(LN2F, logdet, -0.5f * ss - 14.7030165f + sumlog);
}

extern "C" void kernel_launch(void* const* d_in, const int* in_sizes, int n_in,
                              void* d_out, int out_size, void* d_ws, size_t ws_size,
                              hipStream_t stream)
{
  const float* x    = (const float*)d_in[0];
  const float* W0   = (const float*)d_in[1];
  const float* b0   = (const float*)d_in[2];
  const float* W1   = (const float*)d_in[3];
  const float* b1   = (const float*)d_in[4];
  const float* W2   = (const float*)d_in[5];
  const float* b2   = (const float*)d_in[6];
  const float* Wout = (const float*)d_in[7];
  const float* bout = (const float*)d_in[8];
  const float* scale= (const float*)d_in[9];
  const float* shift= (const float*)d_in[10];

  int B = in_sizes[0] / 16;

  hipLaunchKernelGGL(prep_kernel, dim3(103), dim3(256), 0, stream,
                     W0, b0, W1, b1, W2, Wout, bout, scale, (char*)d_ws);

  hipLaunchKernelGGL(flow_kernel, dim3(B / 256), dim3(256), LDS_BYTES, stream,
                     x, b2, scale, shift,
                     (const char*)d_ws, (float*)d_out, B);
}

// Round 8
// 191.958 us; speedup vs baseline: 1.1324x; 1.1324x over previous
//
#include <hip/hip_runtime.h>
#include <math.h>

typedef _Float16 f16;
typedef _Float16 half8 __attribute__((ext_vector_type(8)));
typedef float f32x16 __attribute__((ext_vector_type(16)));

#define DEV __device__ __forceinline__

// ---------------- workspace layout (bytes) ----------------
#define W1F_OFF 0        // [L][nt2]      : 16 frags  = 16 KB   (x 2*log2e)
#define W2F_OFF 16384    // [L][kt4][nt2] : 64 frags  = 64 KB   (unscaled)
#define WOF_OFF 81920    // [L][u8][kt4]  : 256 frags = 256 KB  (x log2e)
#define BOF_OFF 344064   // [L][u8][32] fp32 (legacy col-bias, unused by flow)
#define SUMLOG_OFF 352256 // 1 fp32: sum over all layers/features of log|scale|
#define W0S_OFF 352320   // [L][16][16] f32 W0 x 2*log2e = 8 KB
#define B0S_OFF 360512   // [L][16]     f32 b0 x 2*log2e = 512 B
#define B1S_OFF 361088   // [L][64]     f32 b1 x 2*log2e = 2 KB (end 363136)
#define BOT_OFF 363136   // [L][u8][khi2][16] f32 bout ROW-vector for D^T acc
                         // init (x log2e, softplus offset folded) = 8 KB (end 371328)

// ---------------- LDS layout (bytes, per block of 256 samples) -------------
// (round-5 proven layout: all strides conflict-free, SQ_LDS_BANK_CONFLICT=0)
#define H0_OFF    0       // [256][48]  : 16 f16/sample
#define H0_STRIDE 48
#define H_OFF     12288   // [256][144] : 64 f16/sample (128+16 pad)
#define H_STRIDE  144
#define P_OFF     49152   // [256][116] : 29 fp32/sample (stride 29 dwords, conflict-free b32)
#define P_STRIDE  116
#define LDS_BYTES 78848

DEV float frcp(float x){ return __builtin_amdgcn_rcpf(x); }

#if __has_builtin(__builtin_amdgcn_exp2f)
DEV float fexp2(float x){ return __builtin_amdgcn_exp2f(x); }
#else
DEV float fexp2(float x){ return exp2f(x); }
#endif
#if __has_builtin(__builtin_amdgcn_logf)
DEV float flog2(float x){ return __builtin_amdgcn_logf(x); }
#else
DEV float flog2(float x){ return log2f(x); }
#endif

#define LN2F    0.69314718056f
#define LOG2EF  1.4426950409f
#define TWOLOG2EF 2.8853900818f

// tanh with PRE-SCALED input: x' = 2*log2e * x_linear.
// tanh = 1 - 2/(2^{x'}+1). Robust without clamp. 4 instructions.
DEV float ftanh2(float x){
  float e = fexp2(x);
  float r = frcp(e + 1.f);
  return fmaf(-2.f, r, 1.f);
}

// Rational-quadratic spline forward + log-det (fp32, per-thread).
// p is in LOG2 DOMAIN: p[0..24] = linear_params * log2e (softplus offset
// already folded into p[16..24] at prep). ld_out in LOG2 units.
DEV void rq_spline(const float p[25], float xv, float &y_out, float &ld_out)
{
  float ew[8]; float sw = 0.f;
#pragma unroll
  for (int k = 0; k < 8; ++k){ ew[k] = fexp2(p[k]); sw += ew[k]; }
  float rw = frcp(sw) * 19.9992f;           // (RMAX-RMIN) - K*MIN_BIN

  float xpos[9];
  xpos[0] = -10.f;
#pragma unroll
  for (int k = 0; k < 8; ++k) xpos[k + 1] = xpos[k] + fmaf(ew[k], rw, 1e-4f);

  bool b[8];
  int idx = 0;
#pragma unroll
  for (int j = 1; j < 8; ++j){ b[j] = (xv >= xpos[j]); idx += b[j] ? 1 : 0; }

  float xk = xpos[0], ewk = ew[0];
#pragma unroll
  for (int j = 1; j < 8; ++j){
    xk  = b[j] ? xpos[j] : xk;
    ewk = b[j] ? ew[j]   : ewk;
  }
  float bw = fmaf(ewk, rw, 1e-4f);

  float eh[8]; float shs = 0.f;
#pragma unroll
  for (int k = 0; k < 8; ++k){ eh[k] = fexp2(p[8 + k]); shs += eh[k]; }
  float rh = frcp(shs) * 19.9992f;

  float S = 0.f, ehk = eh[0];
#pragma unroll
  for (int k = 1; k < 8; ++k){
    S   += b[k] ? eh[k - 1] : 0.f;
    ehk  = b[k] ? eh[k]     : ehk;
  }
  float yk = fmaf(S, rh, fmaf((float)idx, 1e-4f, -10.f));
  float bh = fmaf(ehk, rh, 1e-4f);

  float vA = p[16], vB = p[17];
#pragma unroll
  for (int j = 1; j < 8; ++j){
    vA = b[j] ? p[16 + j] : vA;
    vB = b[j] ? p[17 + j] : vB;
  }
  // softplus in log2 domain: ln(1+e^u) = ln2*(max(v,0)+log2(1+2^{-|v|}))
  float tA = fmaxf(vA, 0.f) + flog2(1.f + fexp2(-fabsf(vA)));
  float dk  = fmaf(LN2F, tA, 1e-4f);
  float tB = fmaxf(vB, 0.f) + flog2(1.f + fexp2(-fabsf(vB)));
  float dk1 = fmaf(LN2F, tB, 1e-4f);

  float rbw = frcp(bw);
  float s   = bh * rbw;
  float zf  = fminf(fmaxf((xv - xk) * rbw, 0.f), 1.f);
  float z1  = 1.f - zf;
  float zz  = zf * zf, z01 = zf * z1;
  float den = s + (dk1 + dk - 2.f * s) * z01;
  float rden = frcp(den);
  float yv  = yk + bh * (s * zz + dk * z01) * rden;
  float num = dk1 * zz + 2.f * s * z01 + dk * z1 * z1;
  float ldv2 = flog2(s * s * num * rden * rden);   // log2-domain

  bool outside = (xv <= -10.f) || (xv >= 10.f);
  y_out  = outside ? xv : yv;
  ld_out = outside ? 0.f : ldv2;
}

// ---------------- prep kernel: pack fp16 B-fragments into ws ----------------
// Scaling folded in: W1/b1/W0/b0 x 2*log2e (tanh exp2 path), Wout/bout
// x log2e (+ softplus offset into params 16..24). W2/b2 UNscaled.
extern "C" __global__ void __launch_bounds__(256)
prep_kernel(const float* __restrict__ W0, const float* __restrict__ b0,
            const float* __restrict__ W1, const float* __restrict__ b1,
            const float* __restrict__ W2,
            const float* __restrict__ Wo, const float* __restrict__ bout,
            const float* __restrict__ scale, char* __restrict__ ws)
{
  int tid = blockIdx.x * 256 + threadIdx.x;
  if (tid < 1024){                       // W1 frags: [L][nt2]  (x 2*log2e)
    int fi = tid >> 6, lane = tid & 63;
    int l = fi >> 1, nt = fi & 1;
    int n = nt * 32 + (lane & 31), khi = lane >> 5;
    half8 h;
#pragma unroll
    for (int j = 0; j < 8; ++j){ int k = khi * 8 + j; h[j] = (f16)(W1[l * 1024 + k * 64 + n] * TWOLOG2EF); }
    *(half8*)(ws + W1F_OFF + fi * 1024 + lane * 16) = h;
  } else if (tid < 5120){                // W2 frags: [L][kt4][nt2] (unscaled)
    int idx = tid - 1024;
    int fi = idx >> 6, lane = idx & 63;
    int l = fi >> 3, kt = (fi >> 1) & 3, nt = fi & 1;
    int n = nt * 32 + (lane & 31), khi = lane >> 5;
    half8 h;
#pragma unroll
    for (int j = 0; j < 8; ++j){ int k = kt * 16 + khi * 8 + j; h[j] = (f16)W2[l * 4096 + k * 64 + n]; }
    *(half8*)(ws + W2F_OFF + fi * 1024 + lane * 16) = h;
  } else if (tid < 21504){               // Wout used-col frags: [L][u8][kt4] (x log2e)
    int idx = tid - 5120;
    int fi = idx >> 6, lane = idx & 63;
    int l = fi >> 5, u = (fi >> 2) & 7, kt = fi & 3;
    int f = (l & 1) + 2 * u;
    int c = lane & 31, khi = lane >> 5;
    half8 h;
#pragma unroll
    for (int j = 0; j < 8; ++j){
      int k = kt * 16 + khi * 8 + j;
      float v = (c < 25) ? Wo[l * 25600 + k * 400 + f * 25 + c] * LOG2EF : 0.f;
      h[j] = (f16)v;
    }
    *(half8*)(ws + WOF_OFF + fi * 1024 + lane * 16) = h;
  } else if (tid < 23552){               // legacy col-bias (unused by flow now)
    int idx = tid - 21504;
    int l = idx >> 8, u = (idx >> 5) & 7, c = idx & 31;
    int f = (l & 1) + 2 * u;
    float v = 0.f;
    if (c < 25){
      v = bout[l * 400 + f * 25 + c];
      if (c >= 16) v += 0.54116666f;
      v *= LOG2EF;
    }
    ((float*)(ws + BOF_OFF))[idx] = v;
  } else if (tid == 23552){              // sum of log|scale| over all layers
    float acc = 0.f;
    for (int i = 0; i < 128; ++i) acc += logf(fabsf(scale[i]));
    *(float*)(ws + SUMLOG_OFF) = acc;
  } else if (tid < 25601){               // W0 scaled copy: 2048 floats
    int idx = tid - 23553;
    ((float*)(ws + W0S_OFF))[idx] = W0[idx] * TWOLOG2EF;
  } else if (tid < 25729){               // b0 scaled copy: 128 floats
    int idx = tid - 25601;
    ((float*)(ws + B0S_OFF))[idx] = b0[idx] * TWOLOG2EF;
  } else if (tid < 26241){               // b1 scaled copy: 512 floats
    int idx = tid - 25729;
    ((float*)(ws + B1S_OFF))[idx] = b1[idx] * TWOLOG2EF;
  } else if (tid < 28289){               // BOT row-bias vectors: 2048 floats
    // D^T C/D layout: row r = (i&3) + 8*(i>>2) + 4*khi. botv[i] = bout'[r].
    int idx = tid - 26241;               // = l*256 + u*32 + khi*16 + i
    int l = idx >> 8, u = (idx >> 5) & 7, kh = (idx >> 4) & 1, i = idx & 15;
    int f = (l & 1) + 2 * u;
    int r = (i & 3) + 8 * (i >> 2) + 4 * kh;
    float v = 0.f;
    if (r < 25){
      v = bout[l * 400 + f * 25 + r];
      if (r >= 16) v += 0.54116666f;     // softplus offset folded
      v *= LOG2EF;
    }
    ((float*)(ws + BOT_OFF))[idx] = v;
  }
}

// ---- load the 16-float row-bias vector for (l, u, khi) ----
DEV void load_botv(const char* __restrict__ ws, int l, int u, int khi,
                   float (&botv)[16])
{
  const float4* bp = (const float4*)(ws + BOT_OFF) + ((l * 8 + u) * 2 + khi) * 4;
#pragma unroll
  for (int q = 0; q < 4; ++q){
    float4 v = bp[q];
    botv[q * 4]     = v.x;
    botv[q * 4 + 1] = v.y;
    botv[q * 4 + 2] = v.z;
    botv[q * 4 + 3] = v.w;
  }
}

// ---- one Wout feature: SWAPPED MFMA (D^T = Wout^T . h2^T) + row P-store ---
// bfn acts as the A operand (its packed (lane,j)->(c,k) map is exactly the
// A-fragment layout), a2 as B. D^T: col = sample (ln31 of tile mt), rows =
// param index r = (i&3)+8*(i>>2)+4*khi. Each lane stores 12-13 CONSECUTIVE-
// dword params of its sample (compiler merges to ds_write2/b64), vs the 32
// stride-116B scalar stores of the unswapped form. Bias comes in as the
// row-vector botv (same for both mt tiles).
DEV void wout_feature(const half8 (&a2)[2][4], const half8 (&bfn)[4],
                      const float (&botv)[16], char* lds,
                      int wv, int ln31, int khi)
{
  f32x16 dp[2];
#pragma unroll
  for (int mt = 0; mt < 2; ++mt)
#pragma unroll
    for (int i = 0; i < 16; ++i) dp[mt][i] = botv[i];
#pragma unroll
  for (int kt = 0; kt < 4; ++kt)
#pragma unroll
    for (int mt = 0; mt < 2; ++mt)
      dp[mt] = __builtin_amdgcn_mfma_f32_32x32x16_f16(bfn[kt], a2[mt][kt], dp[mt], 0, 0, 0);
#pragma unroll
  for (int mt = 0; mt < 2; ++mt){
    int s = wv * 64 + mt * 32 + ln31;              // sample row in block-P
    char* base = lds + P_OFF + s * P_STRIDE + khi * 16;  // +4*khi rows
#pragma unroll
    for (int i = 0; i < 12; ++i){
      int rc = (i & 3) + 8 * (i >> 2);             // 0..3, 8..11, 16..19
      *(float*)(base + rc * 4) = dp[mt][i];        // r = rc + 4*khi <= 23
    }
    if (khi == 0)                                  // r = 24 (khi=1 -> 28, skip)
      *(float*)(base + 24 * 4) = dp[mt][12];
  }
}

// ---------------- one coupling layer (all LDS traffic wave-private) --------
// Round-5 proven structure: 64 samples/wave, 1 lane/sample, single P slot.
// (2-lane split and dual-register-p pipelines both measured slower: the
// former adds shfl overhead, the latter spills 25 dwords/layer. Don't redo.)
template<int PAR>
DEV void layer_mfma(int l,
                    const float* __restrict__ b2v,
                    const float* __restrict__ scv, const float* __restrict__ shv,
                    const char* __restrict__ ws, char* lds,
                    float (&z)[16], float &logdet,
                    int t, int lane, int wv, int ln31, int khi)
{
  const float* w0  = (const float*)(ws + W0S_OFF) + l * 256;   // x 2*log2e
  const float* bb0 = (const float*)(ws + B0S_OFF) + l * 16;    // x 2*log2e
  const int rowbase = khi * 4;     // C/D layout: row = (i&3)+8*(i>>2)+4*(lane>>5)

  // ---- hoisted weight-fragment loads (latency hidden behind h0 VALU) ----
  const half8* W1F = (const half8*)(ws + W1F_OFF);
  const half8* W2F = (const half8*)(ws + W2F_OFF);
  half8 w1f[2];
#pragma unroll
  for (int nt = 0; nt < 2; ++nt) w1f[nt] = W1F[(l * 2 + nt) * 64 + lane];
  half8 w2f[8];
#pragma unroll
  for (int kt = 0; kt < 4; ++kt)
#pragma unroll
    for (int nt = 0; nt < 2; ++nt)
      w2f[kt * 2 + nt] = W2F[((l * 4 + kt) * 2 + nt) * 64 + lane];
  float bias1[2], bias2[2];
#pragma unroll
  for (int nt = 0; nt < 2; ++nt){
    bias1[nt] = ((const float*)(ws + B1S_OFF))[l * 64 + nt * 32 + ln31]; // x 2*log2e
    bias2[nt] = b2v[l * 64 + nt * 32 + ln31];                            // unscaled
  }

  // ---- h0 = tanh(mz @ W0 + b0), per-thread VALU (weights pre-scaled) ----
  float h0[16];
#pragma unroll
  for (int j = 0; j < 16; ++j) h0[j] = bb0[j];
#pragma unroll
  for (int u = 0; u < 8; ++u){
    const int f = (1 - PAR) + 2 * u;
    const float v = z[f];
#pragma unroll
    for (int j = 0; j < 16; ++j) h0[j] = fmaf(v, w0[f * 16 + j], h0[j]);
  }
  {
    half8 lo, hi;
#pragma unroll
    for (int j = 0; j < 8; ++j){ lo[j] = (f16)ftanh2(h0[j]); hi[j] = (f16)ftanh2(h0[8 + j]); }
    *(half8*)(lds + H0_OFF + t * H0_STRIDE)      = lo;
    *(half8*)(lds + H0_OFF + t * H0_STRIDE + 16) = hi;
  }

  // ---- W1: h1 = tanh(h0 @ W1 + b1) via MFMA (bias folded into acc init) ----
  half8 a0[2];
#pragma unroll
  for (int mt = 0; mt < 2; ++mt){
    int s = wv * 64 + mt * 32 + ln31;
    a0[mt] = *(const half8*)(lds + H0_OFF + s * H0_STRIDE + khi * 16);
  }
  f32x16 d1[2][2];
#pragma unroll
  for (int mt = 0; mt < 2; ++mt)
#pragma unroll
    for (int nt = 0; nt < 2; ++nt)
#pragma unroll
      for (int i = 0; i < 16; ++i) d1[mt][nt][i] = bias1[nt];
#pragma unroll
  for (int nt = 0; nt < 2; ++nt)
#pragma unroll
    for (int mt = 0; mt < 2; ++mt)
      d1[mt][nt] = __builtin_amdgcn_mfma_f32_32x32x16_f16(a0[mt], w1f[nt], d1[mt][nt], 0, 0, 0);
#pragma unroll
  for (int mt = 0; mt < 2; ++mt)
#pragma unroll
    for (int nt = 0; nt < 2; ++nt)
#pragma unroll
      for (int i = 0; i < 16; ++i){
        int row = (i & 3) + 8 * (i >> 2) + rowbase;
        int s = wv * 64 + mt * 32 + row;
        float v = ftanh2(d1[mt][nt][i]);
        *(f16*)(lds + H_OFF + s * H_STRIDE + (nt * 32 + ln31) * 2) = (f16)v;
      }

  // ---- W2: h2 = h1 @ W2 + b2 via MFMA (bias folded) ----
  half8 a1[2][4];
#pragma unroll
  for (int mt = 0; mt < 2; ++mt){
    int s = wv * 64 + mt * 32 + ln31;
#pragma unroll
    for (int kt = 0; kt < 4; ++kt)
      a1[mt][kt] = *(const half8*)(lds + H_OFF + s * H_STRIDE + kt * 32 + khi * 16);
  }
  f32x16 d2[2][2];
#pragma unroll
  for (int mt = 0; mt < 2; ++mt)
#pragma unroll
    for (int nt = 0; nt < 2; ++nt)
#pragma unroll
      for (int i = 0; i < 16; ++i) d2[mt][nt][i] = bias2[nt];
#pragma unroll
  for (int kt = 0; kt < 4; ++kt)
#pragma unroll
    for (int nt = 0; nt < 2; ++nt)
#pragma unroll
      for (int mt = 0; mt < 2; ++mt)
        d2[mt][nt] = __builtin_amdgcn_mfma_f32_32x32x16_f16(a1[mt][kt], w2f[kt * 2 + nt], d2[mt][nt], 0, 0, 0);

  // ---- prefetch feature u=0's Wout frags + row-bias (hidden behind epi) ----
  const half8* WOF = (const half8*)(ws + WOF_OFF);
  half8 bfn[4];
#pragma unroll
  for (int kt = 0; kt < 4; ++kt) bfn[kt] = WOF[((l * 8 + 0) * 4 + kt) * 64 + lane];
  float botv[16];
  load_botv(ws, l, 0, khi, botv);

#pragma unroll
  for (int mt = 0; mt < 2; ++mt)
#pragma unroll
    for (int nt = 0; nt < 2; ++nt)
#pragma unroll
      for (int i = 0; i < 16; ++i){
        int row = (i & 3) + 8 * (i >> 2) + rowbase;
        int s = wv * 64 + mt * 32 + row;
        float v = d2[mt][nt][i];
        *(f16*)(lds + H_OFF + s * H_STRIDE + (nt * 32 + ln31) * 2) = (f16)v;
      }

  // ---- h2 A/B-fragments (reused across all 8 features) ----
  half8 a2[2][4];
#pragma unroll
  for (int mt = 0; mt < 2; ++mt){
    int s = wv * 64 + mt * 32 + ln31;
#pragma unroll
    for (int kt = 0; kt < 4; ++kt)
      a2[mt][kt] = *(const half8*)(lds + H_OFF + s * H_STRIDE + kt * 32 + khi * 16);
  }

  // ---- feature-loop software pipeline (r5 schedule, swapped Wout) ----
  // p_{u+1} MFMA + LDS-store issued BEFORE spline(u); per-wave DS program
  // order makes the single P slot safe (reads of p_u precede stores of p_{u+1}).
  wout_feature(a2, bfn, botv, lds, wv, ln31, khi);
#pragma unroll
  for (int kt = 0; kt < 4; ++kt) bfn[kt] = WOF[((l * 8 + 1) * 4 + kt) * 64 + lane];
  load_botv(ws, l, 1, khi, botv);

#pragma unroll 1
  for (int u = 0; u < 8; ++u){
    // read own sample's p for feature u (consecutive dwords -> merged reads)
    float p[25];
#pragma unroll
    for (int j = 0; j < 25; ++j)
      p[j] = *(const float*)(lds + P_OFF + t * P_STRIDE + j * 4);

    // issue next feature's MFMA + store before the spline
    if (u < 7){
      wout_feature(a2, bfn, botv, lds, wv, ln31, khi);
      if (u < 6){
#pragma unroll
        for (int kt = 0; kt < 4; ++kt) bfn[kt] = WOF[((l * 8 + u + 2) * 4 + kt) * 64 + lane];
        load_botv(ws, l, u + 2, khi, botv);
      }
    }

    const int f = PAR + 2 * u;
    float y, ld;
    rq_spline(p, z[f], y, ld);
    z[f] = y;
    logdet += ld;                       // log2-domain accumulation
  }

  // ---- affine (log|scale| sum precomputed in prep) ----
  const float* scp = scv + l * 16;
  const float* shp = shv + l * 16;
#pragma unroll
  for (int j = 0; j < 16; ++j)
    z[j] = fmaf(z[j], scp[j], shp[j]);
}

extern "C" __global__ void __launch_bounds__(256, 2)
flow_kernel(const float* __restrict__ x,
            const float* __restrict__ b2v,
            const float* __restrict__ scv, const float* __restrict__ shv,
            const char* __restrict__ ws, float* __restrict__ out, int B)
{
  extern __shared__ char lds[];
  const int t    = threadIdx.x;
  const int lane = t & 63;
  const int wv   = t >> 6;
  const int ln31 = lane & 31;
  const int khi  = lane >> 5;
  const int g    = blockIdx.x * 256 + t;

  float z[16];
  const float4* xv = reinterpret_cast<const float4*>(x + (size_t)g * 16);
  float4 a0 = xv[0], a1 = xv[1], a2 = xv[2], a3 = xv[3];
  z[0]=a0.x; z[1]=a0.y; z[2]=a0.z; z[3]=a0.w;
  z[4]=a1.x; z[5]=a1.y; z[6]=a1.z; z[7]=a1.w;
  z[8]=a2.x; z[9]=a2.y; z[10]=a2.z; z[11]=a2.w;
  z[12]=a3.x; z[13]=a3.y; z[14]=a3.z; z[15]=a3.w;

  float logdet = 0.f;                 // in log2 units
  for (int l = 7; l >= 0; --l){
    if (l & 1) layer_mfma<1>(l, b2v, scv, shv, ws, lds, z, logdet, t, lane, wv, ln31, khi);
    else       layer_mfma<0>(l, b2v, scv, shv, ws, lds, z, logdet, t, lane, wv, ln31, khi);
  }

  float sumlog = *(const float*)(ws + SUMLOG_OFF);
  float ss = 0.f;
#pragma unroll
  for (int j = 0; j < 16; ++j) ss = fmaf(z[j], z[j], ss);
  out[g] = fmaf(LN2F, logdet, -0.5f * ss - 14.7030165f + sumlog);
}

extern "C" void kernel_launch(void* const* d_in, const int* in_sizes, int n_in,
                              void* d_out, int out_size, void* d_ws, size_t ws_size,
                              hipStream_t stream)
{
  const float* x    = (const float*)d_in[0];
  const float* W0   = (const float*)d_in[1];
  const float* b0   = (const float*)d_in[2];
  const float* W1   = (const float*)d_in[3];
  const float* b1   = (const float*)d_in[4];
  const float* W2   = (const float*)d_in[5];
  const float* b2   = (const float*)d_in[6];
  const float* Wout = (const float*)d_in[7];
  const float* bout = (const float*)d_in[8];
  const float* scale= (const float*)d_in[9];
  const float* shift= (const float*)d_in[10];

  int B = in_sizes[0] / 16;

  hipLaunchKernelGGL(prep_kernel, dim3(111), dim3(256), 0, stream,
                     W0, b0, W1, b1, W2, Wout, bout, scale, (char*)d_ws);

  hipLaunchKernelGGL(flow_kernel, dim3(B / 256), dim3(256), LDS_BYTES, stream,
                     x, b2, scale, shift,
                     (const char*)d_ws, (float*)d_out, B);
}